// Round 3
// baseline (108.685 us; speedup 1.0000x reference)
//
#include <hip/hip_runtime.h>
#include <stdint.h>

// ---------------------------------------------------------------------------
// CnnPatchDropout: out[b,c,h,w] = mask[b, pq] ? embed[pq,c,kh,kw] : batch[...]
// mask derived from jax.random.key(42) via threefry2x32 (partitionable).
// B=64,C=64,H=W=128,KH=KW=8,HP=WP=16,PQ=256. Verified bit-exact (round 1).
// ---------------------------------------------------------------------------

#define BB 64
#define PQ 256

// main-kernel geometry: 16,777,216 float4 total
#define MAIN_BLOCKS 4096
#define MAIN_THREADS 256
#define MAIN_ITERS 16          // 4096*256*16 == 16,777,216 exactly
#define MAIN_STRIDE (MAIN_BLOCKS * MAIN_THREADS)

// native vector type: __builtin_nontemporal_* requires scalar/vector, not the
// HIP_vector_type struct
typedef float f32x4 __attribute__((ext_vector_type(4)));

__device__ __forceinline__ uint32_t rotl32(uint32_t v, int r) {
  return (v << r) | (v >> (32 - r));
}

// JAX threefry2x32 block: key (k0,k1), counter (x0,x1).
__device__ __forceinline__ void tf2x32(uint32_t k0, uint32_t k1,
                                       uint32_t x0, uint32_t x1,
                                       uint32_t& o0, uint32_t& o1) {
  uint32_t ks2 = k0 ^ k1 ^ 0x1BD11BDAu;
  x0 += k0; x1 += k1;
#define TFR(r) { x0 += x1; x1 = rotl32(x1, (r)); x1 ^= x0; }
  TFR(13) TFR(15) TFR(26) TFR(6)   x0 += k1;  x1 += ks2 + 1u;
  TFR(17) TFR(29) TFR(16) TFR(24)  x0 += ks2; x1 += k0  + 2u;
  TFR(13) TFR(15) TFR(26) TFR(6)   x0 += k0;  x1 += k1  + 3u;
  TFR(17) TFR(29) TFR(16) TFR(24)  x0 += k1;  x1 += ks2 + 4u;
  TFR(13) TFR(15) TFR(26) TFR(6)   x0 += ks2; x1 += k0  + 5u;
#undef TFR
  o0 = x0; o1 = x1;
}

// Partitionable random_bits (32-bit): XOR-fold the two cipher outputs.
__device__ __forceinline__ uint32_t tf_fold(uint32_t k0, uint32_t k1,
                                            uint32_t c_hi, uint32_t c_lo) {
  uint32_t a, b;
  tf2x32(k0, k1, c_hi, c_lo, a, b);
  return a ^ b;
}

// uniform[0,1): bitcast((bits>>9)|0x3f800000) - 1.0f
__device__ __forceinline__ float bits_to_unif(uint32_t bits) {
  return __uint_as_float((bits >> 9) | 0x3f800000u) - 1.0f;
}

// One block per image b: mask[b][0..255].
__global__ __launch_bounds__(256) void mask_kernel(unsigned char* __restrict__ mask) {
  __shared__ uint32_t keybits[PQ];
  __shared__ int s_dropped;
  __shared__ int s_apply;

  const int b = blockIdx.x;
  const int p = threadIdx.x;

  // split(key(42), 3): k_i = full TF output pair at counter (0, i).
  uint32_t k3a, k3b; tf2x32(0u, 42u, 0u, 2u, k3a, k3b);

  // r[b,p] mantissa-order bits (monotone proxy for the uniform float)
  const uint32_t rb = tf_fold(k3a, k3b, 0u, (uint32_t)(b * PQ + p)) >> 9;
  keybits[p] = rb;

  if (p == 0) {
    uint32_t k1a, k1b; tf2x32(0u, 42u, 0u, 0u, k1a, k1b);
    uint32_t k2a, k2b; tf2x32(0u, 42u, 0u, 1u, k2a, k2b);
    float u1 = bits_to_unif(tf_fold(k1a, k1b, 0u, (uint32_t)b));
    float u2 = bits_to_unif(tf_fold(k2a, k2b, 0u, (uint32_t)b));
    s_apply = (u1 < 0.5f) ? 1 : 0;
    float frac = u2 * 0.4f;   // separate mul then add: mirror XLA (no FMA)
    frac = frac + 0.1f;
    s_dropped = (int)floorf(frac * 256.0f);
  }
  __syncthreads();

  // stable rank of r[b,p] within row b == argsort(argsort(r))[b,p]
  int rank = 0;
  for (int q = 0; q < PQ; ++q) {
    uint32_t o = keybits[q];           // broadcast read: conflict-free
    rank += (o < rb) || (o == rb && q < p);
  }
  mask[b * PQ + p] = (s_apply && rank < s_dropped) ? 1 : 0;
}

// Main copy/select. 16 float4 per thread, compile-time-constant trip count
// (fully unrolled, no bounds check). Non-temporal on the touch-once streams
// (batch in, out) to keep the reused embed (4 MB) + mask resident in L2.
__global__ __launch_bounds__(MAIN_THREADS) void patch_dropout_kernel(
    const f32x4* __restrict__ batch,
    const f32x4* __restrict__ embed,
    const unsigned char* __restrict__ mask,
    f32x4* __restrict__ out) {
  const int tid = blockIdx.x * MAIN_THREADS + threadIdx.x;
#pragma unroll
  for (int it = 0; it < MAIN_ITERS; ++it) {
    const int i = tid + it * MAIN_STRIDE;
    // i indexes float4s: w4=i&31 (W/4=32), h=(i>>5)&127, c=(i>>12)&63, b=i>>18
    const int w4 = i & 31;
    const int h  = (i >> 5) & 127;
    const int c  = (i >> 12) & 63;
    const int b  = i >> 18;
    const int pq = ((h >> 3) << 4) | (w4 >> 1);   // hp*16 + wp

    f32x4 v;
    if (mask[(b << 8) | pq]) {
      // embed flat float idx = pq*4096 + c*64 + kh*8 + kw ; /4 -> float4 idx
      v = embed[(pq << 10) + (c << 4) + ((h & 7) << 1) + (w4 & 1)];
    } else {
      v = __builtin_nontemporal_load(&batch[i]);
    }
    __builtin_nontemporal_store(v, &out[i]);
  }
}

extern "C" void kernel_launch(void* const* d_in, const int* in_sizes, int n_in,
                              void* d_out, int out_size, void* d_ws, size_t ws_size,
                              hipStream_t stream) {
  const float* batch = (const float*)d_in[0];
  const float* embed = (const float*)d_in[1];
  float* out = (float*)d_out;
  unsigned char* mask = (unsigned char*)d_ws;   // 16 KB scratch

  mask_kernel<<<BB, 256, 0, stream>>>(mask);

  patch_dropout_kernel<<<MAIN_BLOCKS, MAIN_THREADS, 0, stream>>>(
      (const f32x4*)batch, (const f32x4*)embed, mask, (f32x4*)out);
}

// Round 4
// 92.045 us; speedup vs baseline: 1.1808x; 1.1808x over previous
//
#include <hip/hip_runtime.h>
#include <stdint.h>

// ---------------------------------------------------------------------------
// CnnPatchDropout: out[b,c,h,w] = mask[b, pq] ? embed[pq,c,kh,kw] : batch[...]
// mask derived from jax.random.key(42) via threefry2x32 (partitionable).
// B=64,C=64,H=W=128,KH=KW=8,HP=WP=16,PQ=256. Verified bit-exact (round 1).
//
// Round-4 A/B: exact round-1 geometry (65536 blocks x 1 float4/thread, plain
// cached loads — 101.7 us) with ONLY the store switched to non-temporal.
// Rationale: batch (268 MB) is ~L3-resident across graph replays (round-3
// FETCH=137MB < 228MB live reads); nt-LOAD discards that reuse (regressed).
// nt-STORE should free L2/L3 allocation for the read stream.
// ---------------------------------------------------------------------------

#define BB 64
#define PQ 256

// native vector type: __builtin_nontemporal_* rejects HIP_vector_type struct
typedef float f32x4 __attribute__((ext_vector_type(4)));

__device__ __forceinline__ uint32_t rotl32(uint32_t v, int r) {
  return (v << r) | (v >> (32 - r));
}

// JAX threefry2x32 block: key (k0,k1), counter (x0,x1).
__device__ __forceinline__ void tf2x32(uint32_t k0, uint32_t k1,
                                       uint32_t x0, uint32_t x1,
                                       uint32_t& o0, uint32_t& o1) {
  uint32_t ks2 = k0 ^ k1 ^ 0x1BD11BDAu;
  x0 += k0; x1 += k1;
#define TFR(r) { x0 += x1; x1 = rotl32(x1, (r)); x1 ^= x0; }
  TFR(13) TFR(15) TFR(26) TFR(6)   x0 += k1;  x1 += ks2 + 1u;
  TFR(17) TFR(29) TFR(16) TFR(24)  x0 += ks2; x1 += k0  + 2u;
  TFR(13) TFR(15) TFR(26) TFR(6)   x0 += k0;  x1 += k1  + 3u;
  TFR(17) TFR(29) TFR(16) TFR(24)  x0 += k1;  x1 += ks2 + 4u;
  TFR(13) TFR(15) TFR(26) TFR(6)   x0 += ks2; x1 += k0  + 5u;
#undef TFR
  o0 = x0; o1 = x1;
}

// Partitionable random_bits (32-bit): XOR-fold the two cipher outputs.
__device__ __forceinline__ uint32_t tf_fold(uint32_t k0, uint32_t k1,
                                            uint32_t c_hi, uint32_t c_lo) {
  uint32_t a, b;
  tf2x32(k0, k1, c_hi, c_lo, a, b);
  return a ^ b;
}

// uniform[0,1): bitcast((bits>>9)|0x3f800000) - 1.0f
__device__ __forceinline__ float bits_to_unif(uint32_t bits) {
  return __uint_as_float((bits >> 9) | 0x3f800000u) - 1.0f;
}

// One block per image b: mask[b][0..255].
__global__ __launch_bounds__(256) void mask_kernel(unsigned char* __restrict__ mask) {
  __shared__ uint32_t keybits[PQ];
  __shared__ int s_dropped;
  __shared__ int s_apply;

  const int b = blockIdx.x;
  const int p = threadIdx.x;

  // split(key(42), 3): k_i = full TF output pair at counter (0, i).
  uint32_t k3a, k3b; tf2x32(0u, 42u, 0u, 2u, k3a, k3b);

  // r[b,p] mantissa-order bits (monotone proxy for the uniform float)
  const uint32_t rb = tf_fold(k3a, k3b, 0u, (uint32_t)(b * PQ + p)) >> 9;
  keybits[p] = rb;

  if (p == 0) {
    uint32_t k1a, k1b; tf2x32(0u, 42u, 0u, 0u, k1a, k1b);
    uint32_t k2a, k2b; tf2x32(0u, 42u, 0u, 1u, k2a, k2b);
    float u1 = bits_to_unif(tf_fold(k1a, k1b, 0u, (uint32_t)b));
    float u2 = bits_to_unif(tf_fold(k2a, k2b, 0u, (uint32_t)b));
    s_apply = (u1 < 0.5f) ? 1 : 0;
    float frac = u2 * 0.4f;   // separate mul then add: mirror XLA (no FMA)
    frac = frac + 0.1f;
    s_dropped = (int)floorf(frac * 256.0f);
  }
  __syncthreads();

  // stable rank of r[b,p] within row b == argsort(argsort(r))[b,p]
  int rank = 0;
  for (int q = 0; q < PQ; ++q) {
    uint32_t o = keybits[q];           // broadcast read: conflict-free
    rank += (o < rb) || (o == rb && q < p);
  }
  mask[b * PQ + p] = (s_apply && rank < s_dropped) ? 1 : 0;
}

// Main copy/select. One float4 per thread (round-1 geometry). Cached loads
// (batch is L3-resident across replays); non-temporal store only.
__global__ __launch_bounds__(256) void patch_dropout_kernel(
    const f32x4* __restrict__ batch,
    const f32x4* __restrict__ embed,
    const unsigned char* __restrict__ mask,
    f32x4* __restrict__ out, int n4) {
  int i = blockIdx.x * blockDim.x + threadIdx.x;
  if (i >= n4) return;
  // i indexes float4s: w4 = i&31 (W/4=32), h = (i>>5)&127, c = (i>>12)&63, b = i>>18
  const int w4 = i & 31;
  const int h  = (i >> 5) & 127;
  const int c  = (i >> 12) & 63;
  const int b  = i >> 18;
  const int pq = ((h >> 3) << 4) | (w4 >> 1);   // hp*16 + wp

  f32x4 v;
  if (mask[(b << 8) | pq]) {
    // embed flat float idx = pq*4096 + c*64 + kh*8 + kw ; /4 -> float4 idx
    v = embed[(pq << 10) + (c << 4) + ((h & 7) << 1) + (w4 & 1)];
  } else {
    v = batch[i];
  }
  __builtin_nontemporal_store(v, &out[i]);
}

extern "C" void kernel_launch(void* const* d_in, const int* in_sizes, int n_in,
                              void* d_out, int out_size, void* d_ws, size_t ws_size,
                              hipStream_t stream) {
  const float* batch = (const float*)d_in[0];
  const float* embed = (const float*)d_in[1];
  float* out = (float*)d_out;
  unsigned char* mask = (unsigned char*)d_ws;   // 16 KB scratch

  mask_kernel<<<BB, 256, 0, stream>>>(mask);

  const int n4 = out_size / 4;                  // 16,777,216
  const int blocks = (n4 + 255) / 256;          // 65,536
  patch_dropout_kernel<<<blocks, 256, 0, stream>>>(
      (const f32x4*)batch, (const f32x4*)embed, mask, (f32x4*)out, n4);
}